// Round 4
// baseline (265.069 us; speedup 1.0000x reference)
//
#include <hip/hip_runtime.h>

#define DEVINL __device__ __forceinline__

// lower-tri packed index, requires i >= j
#define TIX(i, j) ((i) * ((i) + 1) / 2 + (j))
// symmetric access (compile-time resolved under full unroll)
#define SYM(arr, i, j) ((i) >= (j) ? arr[TIX(i, j)] : arr[TIX(j, i)])

DEVINL void inv4(const float* m, float* inv) {
    float s0 = m[0] * m[5] - m[1] * m[4];
    float s1 = m[0] * m[6] - m[2] * m[4];
    float s2 = m[0] * m[7] - m[3] * m[4];
    float s3 = m[1] * m[6] - m[2] * m[5];
    float s4 = m[1] * m[7] - m[3] * m[5];
    float s5 = m[2] * m[7] - m[3] * m[6];
    float c5 = m[10] * m[15] - m[11] * m[14];
    float c4 = m[9] * m[15] - m[11] * m[13];
    float c3 = m[9] * m[14] - m[10] * m[13];
    float c2 = m[8] * m[15] - m[11] * m[12];
    float c1 = m[8] * m[14] - m[10] * m[12];
    float c0 = m[8] * m[13] - m[9] * m[12];
    float det = s0 * c5 - s1 * c4 + s2 * c3 + s3 * c2 - s4 * c1 + s5 * c0;
    float id = 1.0f / det;
    inv[0]  = ( m[5] * c5 - m[6] * c4 + m[7] * c3) * id;
    inv[1]  = (-m[1] * c5 + m[2] * c4 - m[3] * c3) * id;
    inv[2]  = ( m[13] * s5 - m[14] * s4 + m[15] * s3) * id;
    inv[3]  = (-m[9] * s5 + m[10] * s4 - m[11] * s3) * id;
    inv[4]  = (-m[4] * c5 + m[6] * c2 - m[7] * c1) * id;
    inv[5]  = ( m[0] * c5 - m[2] * c2 + m[3] * c1) * id;
    inv[6]  = (-m[12] * s5 + m[14] * s2 - m[15] * s1) * id;
    inv[7]  = ( m[8] * s5 - m[10] * s2 + m[11] * s1) * id;
    inv[8]  = ( m[4] * c4 - m[5] * c2 + m[7] * c0) * id;
    inv[9]  = (-m[0] * c4 + m[1] * c2 - m[3] * c0) * id;
    inv[10] = ( m[12] * s4 - m[13] * s2 + m[15] * s0) * id;
    inv[11] = (-m[8] * s4 + m[9] * s2 - m[11] * s0) * id;
    inv[12] = (-m[4] * c3 + m[5] * c1 - m[6] * c0) * id;
    inv[13] = ( m[0] * c3 - m[1] * c1 + m[2] * c0) * id;
    inv[14] = (-m[12] * s3 + m[13] * s1 - m[14] * s0) * id;
    inv[15] = ( m[8] * s3 - m[9] * s1 + m[10] * s0) * id;
}

// One thread per batch. Direct (per-thread strided) global loads — no input
// staging barriers, so loads stay in flight across compute (no vmcnt(0)
// drains until output staging). Register budget engineered for <=128 VGPR
// (16 waves/CU):
//  - F streamed in row-halves through one reused 32-reg array
//  - Q deferred until F is dead
//  - K never materialized: us = ns + HP^T(Si res); cov = Pn - HP^T(Si HP),
//    accumulated in place into packed Pn (symmetric, mirrored on write)
// Outputs coalesced through a 36.9 KB LDS arena (4 blocks/CU fits 147 KB).
__global__ __launch_bounds__(256) void ekf_kernel(
    const float* __restrict__ meas,   // (B,4)
    const float* __restrict__ state,  // (B,8)
    const float* __restrict__ Pin,    // (B,8,8) symmetric
    const float* __restrict__ Fin,    // (B,8,8)
    const float* __restrict__ Hin,    // (B,4,8)
    const float* __restrict__ pnin,   // (B,36)
    const float* __restrict__ mnin,   // (B,10)
    float* __restrict__ out_pred,     // (B,4)
    float* __restrict__ out_state,    // (B,8)
    float* __restrict__ out_cov)      // (B,8,8)
{
    const int t  = threadIdx.x;
    const int bb = blockIdx.x * 256;
    const int b  = bb + t;

    __shared__ float4 buf[2304];      // 256 * 9 float4 = 36,864 B (outputs only)

    // ---------- state ----------
    float s[8];
    {
        const float4* g = reinterpret_cast<const float4*>(state) + (size_t)b * 2;
        float4 a = g[0], c = g[1];
        s[0] = a.x; s[1] = a.y; s[2] = a.z; s[3] = a.w;
        s[4] = c.x; s[5] = c.y; s[6] = c.z; s[7] = c.w;
    }

    // ---------- P (full 8x8 load, keep packed lower-tri 36) ----------
    float Ps[36];
    {
        const float4* g = reinterpret_cast<const float4*>(Pin) + (size_t)b * 16;
        #pragma unroll
        for (int i = 0; i < 16; ++i) {
            float4 v = g[i];
            const int row = i / 2, c0 = (i % 2) * 4;
            if (c0 + 0 <= row) Ps[TIX(row, c0 + 0)] = v.x;
            if (c0 + 1 <= row) Ps[TIX(row, c0 + 1)] = v.y;
            if (c0 + 2 <= row) Ps[TIX(row, c0 + 2)] = v.z;
            if (c0 + 3 <= row) Ps[TIX(row, c0 + 3)] = v.w;
        }
    }

    float Pn[36];   // new_state_cov, packed; Q added after F dies
    float ns[8];    // predicted state
    float Ta[32];   // Ta[l*8+j] = (P F^T)[j][l], l in 0..3

    // ---------- F half A (rows 0..3) ----------
    {
        float Fh[32];
        {
            const float4* g = reinterpret_cast<const float4*>(Fin) + (size_t)b * 16;
            #pragma unroll
            for (int i = 0; i < 8; ++i) {
                float4 v = g[i];
                Fh[4 * i] = v.x; Fh[4 * i + 1] = v.y; Fh[4 * i + 2] = v.z; Fh[4 * i + 3] = v.w;
            }
        }
        #pragma unroll
        for (int i = 0; i < 4; ++i) {
            float acc = 0.f;
            #pragma unroll
            for (int j = 0; j < 8; ++j) acc += Fh[i * 8 + j] * s[j];
            ns[i] = acc;
        }
        // Ta[l][j] = P row j . F row l
        #pragma unroll
        for (int l = 0; l < 4; ++l)
            #pragma unroll
            for (int j = 0; j < 8; ++j) {
                float acc = 0.f;
                #pragma unroll
                for (int k = 0; k < 8; ++k) acc += SYM(Ps, j, k) * Fh[l * 8 + k];
                Ta[l * 8 + j] = acc;
            }
        // newP_AA: i,l in 0..3, l <= i
        #pragma unroll
        for (int i = 0; i < 4; ++i)
            #pragma unroll
            for (int l = 0; l <= i; ++l) {
                float acc = 0.f;
                #pragma unroll
                for (int j = 0; j < 8; ++j) acc += Fh[i * 8 + j] * Ta[l * 8 + j];
                Pn[TIX(i, l)] = acc;
            }
    }

    // ---------- F half B (rows 4..7) ----------
    {
        float Fh[32];
        {
            const float4* g = reinterpret_cast<const float4*>(Fin) + (size_t)b * 16;
            #pragma unroll
            for (int i = 0; i < 8; ++i) {
                float4 v = g[8 + i];
                Fh[4 * i] = v.x; Fh[4 * i + 1] = v.y; Fh[4 * i + 2] = v.z; Fh[4 * i + 3] = v.w;
            }
        }
        #pragma unroll
        for (int r = 0; r < 4; ++r) {
            float acc = 0.f;
            #pragma unroll
            for (int j = 0; j < 8; ++j) acc += Fh[r * 8 + j] * s[j];
            ns[4 + r] = acc;
        }
        // newP_BA: i in 4..7, l in 0..3 (uses Ta, then Ta dies)
        #pragma unroll
        for (int r = 0; r < 4; ++r)
            #pragma unroll
            for (int l = 0; l < 4; ++l) {
                float acc = 0.f;
                #pragma unroll
                for (int j = 0; j < 8; ++j) acc += Fh[r * 8 + j] * Ta[l * 8 + j];
                Pn[TIX(4 + r, l)] = acc;
            }
        // Tb[r][j] = P row j . F row (4+r)   (then Ps dies)
        float Tb[32];
        #pragma unroll
        for (int r = 0; r < 4; ++r)
            #pragma unroll
            for (int j = 0; j < 8; ++j) {
                float acc = 0.f;
                #pragma unroll
                for (int k = 0; k < 8; ++k) acc += SYM(Ps, j, k) * Fh[r * 8 + k];
                Tb[r * 8 + j] = acc;
            }
        // newP_BB: i,l in 4..7, l <= i
        #pragma unroll
        for (int r = 0; r < 4; ++r)
            #pragma unroll
            for (int q = 0; q <= r; ++q) {
                float acc = 0.f;
                #pragma unroll
                for (int j = 0; j < 8; ++j) acc += Fh[r * 8 + j] * Tb[q * 8 + j];
                Pn[TIX(4 + r, 4 + q)] = acc;
            }
    }

    // ---------- deferred Q: Pn += Lq Lq^T ----------
    {
        float Lq[36];
        const float4* g = reinterpret_cast<const float4*>(pnin) + (size_t)b * 9;
        #pragma unroll
        for (int i = 0; i < 9; ++i) {
            float4 v = g[i];
            Lq[4 * i] = v.x; Lq[4 * i + 1] = v.y; Lq[4 * i + 2] = v.z; Lq[4 * i + 3] = v.w;
        }
        #pragma unroll
        for (int i = 0; i < 8; ++i)
            #pragma unroll
            for (int j = 0; j <= i; ++j) {
                float acc = Pn[TIX(i, j)];
                #pragma unroll
                for (int k = 0; k <= j; ++k)
                    acc += Lq[TIX(i, k)] * Lq[TIX(j, k)];
                Pn[TIX(i, j)] = acc;
            }
    }

    // ---------- H, R, meas ----------
    float Hm[32];
    {
        const float4* g = reinterpret_cast<const float4*>(Hin) + (size_t)b * 8;
        #pragma unroll
        for (int i = 0; i < 8; ++i) {
            float4 v = g[i];
            Hm[4 * i] = v.x; Hm[4 * i + 1] = v.y; Hm[4 * i + 2] = v.z; Hm[4 * i + 3] = v.w;
        }
    }
    float Rs[10];
    {
        float Lr[10];
        const float2* g = reinterpret_cast<const float2*>(mnin) + (size_t)b * 5;
        #pragma unroll
        for (int i = 0; i < 5; ++i) {
            float2 v = g[i];
            Lr[2 * i] = v.x; Lr[2 * i + 1] = v.y;
        }
        #pragma unroll
        for (int i = 0; i < 4; ++i)
            #pragma unroll
            for (int j = 0; j <= i; ++j) {
                float acc = 0.f;
                #pragma unroll
                for (int k = 0; k <= j; ++k)
                    acc += Lr[TIX(i, k)] * Lr[TIX(j, k)];
                Rs[TIX(i, j)] = acc;
            }
    }

    // ---------- residual ----------
    float res[4];
    {
        float4 z = *(reinterpret_cast<const float4*>(meas) + b);
        const float zz[4] = {z.x, z.y, z.z, z.w};
        #pragma unroll
        for (int i = 0; i < 4; ++i) {
            float acc = 0.f;
            #pragma unroll
            for (int j = 0; j < 8; ++j) acc += Hm[i * 8 + j] * ns[j];
            // prediction output: coalesced 16B/lane
            res[i] = zz[i] - acc;
            if (i == 3) {
                float4 pv;
                pv.x = zz[0] - res[0]; pv.y = zz[1] - res[1];
                pv.z = zz[2] - res[2]; pv.w = zz[3] - res[3];
                *(reinterpret_cast<float4*>(out_pred) + b) = pv;
            }
        }
    }

    // ---------- HP = H newP (4x8) ----------
    float HP[32];
    #pragma unroll
    for (int i = 0; i < 4; ++i)
        #pragma unroll
        for (int k = 0; k < 8; ++k) {
            float acc = 0.f;
            #pragma unroll
            for (int j = 0; j < 8; ++j) acc += Hm[i * 8 + j] * SYM(Pn, j, k);
            HP[i * 8 + k] = acc;
        }

    // ---------- S = HP H^T + R (sym), invert ----------
    float Si[16];
    {
        float Sf[16];
        #pragma unroll
        for (int i = 0; i < 4; ++i)
            #pragma unroll
            for (int l = 0; l <= i; ++l) {
                float acc = SYM(Rs, i, l);
                #pragma unroll
                for (int k = 0; k < 8; ++k) acc += HP[i * 8 + k] * Hm[l * 8 + k];
                Sf[i * 4 + l] = acc;
                Sf[l * 4 + i] = acc;
            }
        inv4(Sf, Si);
    }
    // Hm dead

    // ---------- upd_state = ns + HP^T (Si res) ----------
    float us[8];
    {
        float w[4];
        #pragma unroll
        for (int a = 0; a < 4; ++a) {
            float acc = 0.f;
            #pragma unroll
            for (int c = 0; c < 4; ++c) acc += Si[a * 4 + c] * res[c];
            w[a] = acc;
        }
        #pragma unroll
        for (int i = 0; i < 8; ++i) {
            float acc = ns[i];
            #pragma unroll
            for (int a = 0; a < 4; ++a) acc += HP[a * 8 + i] * w[a];
            us[i] = acc;
        }
    }

    // ---------- stage upd_state out (pad-3 layout) ----------
    buf[t * 3 + 0] = make_float4(us[0], us[1], us[2], us[3]);
    buf[t * 3 + 1] = make_float4(us[4], us[5], us[6], us[7]);
    __syncthreads();
    {
        float4* g = reinterpret_cast<float4*>(out_state) + (size_t)bb * 2;
        #pragma unroll
        for (int i = 0; i < 2; ++i) {
            int f = i * 256 + t;
            g[f] = buf[(f >> 1) * 3 + (f & 1)];
        }
    }
    __syncthreads();

    // ---------- upd_cov = Pn - HP^T (Si HP), in place (symmetric) ----------
    {
        float M[32];  // M = Si HP  (4x8)
        #pragma unroll
        for (int a = 0; a < 4; ++a)
            #pragma unroll
            for (int j = 0; j < 8; ++j) {
                float acc = 0.f;
                #pragma unroll
                for (int c = 0; c < 4; ++c) acc += Si[a * 4 + c] * HP[c * 8 + j];
                M[a * 8 + j] = acc;
            }
        #pragma unroll
        for (int i = 0; i < 8; ++i)
            #pragma unroll
            for (int l = 0; l <= i; ++l) {
                float acc = Pn[TIX(i, l)];
                #pragma unroll
                for (int a = 0; a < 4; ++a) acc -= HP[a * 8 + i] * M[a * 8 + l];
                Pn[TIX(i, l)] = acc;
            }
    }

    // ---------- cov out: two row-halves through LDS, mirrored from packed ----------
    #pragma unroll
    for (int h = 0; h < 2; ++h) {
        #pragma unroll
        for (int r = 0; r < 4; ++r) {
            const int i = 4 * h + r;
            buf[t * 9 + 2 * r + 0] = make_float4(SYM(Pn, i, 0), SYM(Pn, i, 1),
                                                 SYM(Pn, i, 2), SYM(Pn, i, 3));
            buf[t * 9 + 2 * r + 1] = make_float4(SYM(Pn, i, 4), SYM(Pn, i, 5),
                                                 SYM(Pn, i, 6), SYM(Pn, i, 7));
        }
        __syncthreads();
        {
            float4* g = reinterpret_cast<float4*>(out_cov) + (size_t)bb * 16;
            #pragma unroll
            for (int i = 0; i < 8; ++i) {
                int fl = i * 256 + t;
                int bq = fl >> 3, q = fl & 7;
                g[bq * 16 + 8 * h + q] = buf[bq * 9 + q];
            }
        }
        __syncthreads();
    }
}

extern "C" void kernel_launch(void* const* d_in, const int* in_sizes, int n_in,
                              void* d_out, int out_size, void* d_ws, size_t ws_size,
                              hipStream_t stream) {
    const float* meas  = (const float*)d_in[0];
    const float* state = (const float*)d_in[1];
    const float* Pin   = (const float*)d_in[2];
    const float* Fin   = (const float*)d_in[3];
    const float* Hin   = (const float*)d_in[4];
    const float* pn    = (const float*)d_in[5];
    const float* mn    = (const float*)d_in[6];

    const int B = in_sizes[1] / 8;  // state is (B, 8); B = 262144 (divisible by 256)

    float* out = (float*)d_out;
    float* out_pred  = out;                       // B*4
    float* out_state = out + (size_t)B * 4;       // B*8
    float* out_cov   = out + (size_t)B * 12;      // B*64

    dim3 block(256);
    dim3 grid(B / 256);
    ekf_kernel<<<grid, block, 0, stream>>>(meas, state, Pin, Fin, Hin, pn, mn,
                                           out_pred, out_state, out_cov);
}

// Round 5
// 255.992 us; speedup vs baseline: 1.0355x; 1.0355x over previous
//
#include <hip/hip_runtime.h>

#define DEVINL __device__ __forceinline__

// lower-tri packed index, requires i >= j
#define TIX(i, j) ((i) * ((i) + 1) / 2 + (j))
// symmetric access (compile-time resolved under full unroll)
#define SYM(arr, i, j) ((i) >= (j) ? arr[TIX(i, j)] : arr[TIX(j, i)])

DEVINL void inv4(const float* m, float* inv) {
    float s0 = m[0] * m[5] - m[1] * m[4];
    float s1 = m[0] * m[6] - m[2] * m[4];
    float s2 = m[0] * m[7] - m[3] * m[4];
    float s3 = m[1] * m[6] - m[2] * m[5];
    float s4 = m[1] * m[7] - m[3] * m[5];
    float s5 = m[2] * m[7] - m[3] * m[6];
    float c5 = m[10] * m[15] - m[11] * m[14];
    float c4 = m[9] * m[15] - m[11] * m[13];
    float c3 = m[9] * m[14] - m[10] * m[13];
    float c2 = m[8] * m[15] - m[11] * m[12];
    float c1 = m[8] * m[14] - m[10] * m[12];
    float c0 = m[8] * m[13] - m[9] * m[12];
    float det = s0 * c5 - s1 * c4 + s2 * c3 + s3 * c2 - s4 * c1 + s5 * c0;
    float id = 1.0f / det;
    inv[0]  = ( m[5] * c5 - m[6] * c4 + m[7] * c3) * id;
    inv[1]  = (-m[1] * c5 + m[2] * c4 - m[3] * c3) * id;
    inv[2]  = ( m[13] * s5 - m[14] * s4 + m[15] * s3) * id;
    inv[3]  = (-m[9] * s5 + m[10] * s4 - m[11] * s3) * id;
    inv[4]  = (-m[4] * c5 + m[6] * c2 - m[7] * c1) * id;
    inv[5]  = ( m[0] * c5 - m[2] * c2 + m[3] * c1) * id;
    inv[6]  = (-m[12] * s5 + m[14] * s2 - m[15] * s1) * id;
    inv[7]  = ( m[8] * s5 - m[10] * s2 + m[11] * s1) * id;
    inv[8]  = ( m[4] * c4 - m[5] * c2 + m[7] * c0) * id;
    inv[9]  = (-m[0] * c4 + m[1] * c2 - m[3] * c0) * id;
    inv[10] = ( m[12] * s4 - m[13] * s2 + m[15] * s0) * id;
    inv[11] = (-m[8] * s4 + m[9] * s2 - m[11] * s0) * id;
    inv[12] = (-m[4] * c3 + m[5] * c1 - m[6] * c0) * id;
    inv[13] = ( m[0] * c3 - m[1] * c1 + m[2] * c0) * id;
    inv[14] = (-m[12] * s3 + m[13] * s1 - m[14] * s0) * id;
    inv[15] = ( m[8] * s3 - m[9] * s1 + m[10] * s0) * id;
}

// SINGLE-WAVE blocks: 64 threads = 1 wave = 1 block, one batch per thread.
// Rationale (R3/R4 post-mortem): with 256-thread blocks every staging phase
// rendezvous-barriers 4 waves (vmcnt(0)+s_barrier drains), and at 136 VGPR
// only ~2 blocks/CU overlap -> ~60us of stall. A 1-wave block's barrier is
// wave-local (no partner waves, drains only its own loads), and ~12
// independent blocks/CU free-run in different phases -> latency hidden by TLP.
// Keeps R3's staged-coalesced loads (FETCH 112 vs 146 MB direct) and
// LDS-coalesced stores (WRITE = 78 MB = ideal). K never materialized;
// cov computed in place in packed Pn.
__global__ __launch_bounds__(64) void ekf_kernel(
    const float* __restrict__ meas,   // (B,4)
    const float* __restrict__ state,  // (B,8)
    const float* __restrict__ Pin,    // (B,8,8) symmetric
    const float* __restrict__ Fin,    // (B,8,8)
    const float* __restrict__ Hin,    // (B,4,8)
    const float* __restrict__ pnin,   // (B,36)
    const float* __restrict__ mnin,   // (B,10)
    float* __restrict__ out_pred,     // (B,4)
    float* __restrict__ out_state,    // (B,8)
    float* __restrict__ out_cov)      // (B,8,8)
{
    const int t  = threadIdx.x;
    const int bb = blockIdx.x * 64;
    const int b  = bb + t;

    __shared__ float4 buf[576];       // 64 * 9 float4 = 9,216 B

    // ============ stage pn (9 f4/batch) -> Q into Pn ============
    {
        const float4* g = reinterpret_cast<const float4*>(pnin) + (size_t)bb * 9;
        #pragma unroll
        for (int i = 0; i < 9; ++i) buf[i * 64 + t] = g[i * 64 + t];
    }
    __syncthreads();
    float Pn[36];  // becomes new_state_cov; init with Q
    {
        float Lq[36];
        #pragma unroll
        for (int q = 0; q < 9; ++q) {
            float4 v = buf[t * 9 + q];
            Lq[4 * q] = v.x; Lq[4 * q + 1] = v.y; Lq[4 * q + 2] = v.z; Lq[4 * q + 3] = v.w;
        }
        #pragma unroll
        for (int i = 0; i < 8; ++i)
            #pragma unroll
            for (int j = 0; j <= i; ++j) {
                float acc = 0.f;
                #pragma unroll
                for (int k = 0; k <= j; ++k)
                    acc += Lq[TIX(i, k)] * Lq[TIX(j, k)];
                Pn[TIX(i, j)] = acc;
            }
    }
    // NOTE: no sync before next ds_write phase — single wave executes its
    // instruction stream in order; LDS pipe is FIFO per wave, so the phase-k
    // reads (earlier insts) complete before phase-k+1 writes (later insts).

    // ============ stage state (2 f4/batch, pad-3 layout) ============
    {
        const float4* g = reinterpret_cast<const float4*>(state) + (size_t)bb * 2;
        #pragma unroll
        for (int i = 0; i < 2; ++i) {
            int f = i * 64 + t;
            buf[(f >> 1) * 3 + (f & 1)] = g[f];
        }
    }
    __syncthreads();
    float s[8];
    {
        float4 a = buf[t * 3 + 0], c = buf[t * 3 + 1];
        s[0] = a.x; s[1] = a.y; s[2] = a.z; s[3] = a.w;
        s[4] = c.x; s[5] = c.y; s[6] = c.z; s[7] = c.w;
    }

    // ============ stage P in two halves (8 f4/batch each, pad-9) -> Ps ============
    float Ps[36];
    #pragma unroll
    for (int h = 0; h < 2; ++h) {
        {
            const float4* g = reinterpret_cast<const float4*>(Pin) + (size_t)bb * 16;
            #pragma unroll
            for (int i = 0; i < 8; ++i) {
                int fl = i * 64 + t;
                int bq = fl >> 3, q = fl & 7;
                buf[bq * 9 + q] = g[bq * 16 + 8 * h + q];
            }
        }
        __syncthreads();
        #pragma unroll
        for (int q = 0; q < 8; ++q) {
            float4 v = buf[t * 9 + q];
            const int row = 4 * h + (q >> 1), c0 = 4 * (q & 1);
            if (c0 + 0 <= row) Ps[TIX(row, c0 + 0)] = v.x;
            if (c0 + 1 <= row) Ps[TIX(row, c0 + 1)] = v.y;
            if (c0 + 2 <= row) Ps[TIX(row, c0 + 2)] = v.z;
            if (c0 + 3 <= row) Ps[TIX(row, c0 + 3)] = v.w;
        }
        __syncthreads();
    }

    // ============ stage F in two halves -> Fm[64] ============
    float Fm[64];
    #pragma unroll
    for (int h = 0; h < 2; ++h) {
        {
            const float4* g = reinterpret_cast<const float4*>(Fin) + (size_t)bb * 16;
            #pragma unroll
            for (int i = 0; i < 8; ++i) {
                int fl = i * 64 + t;
                int bq = fl >> 3, q = fl & 7;
                buf[bq * 9 + q] = g[bq * 16 + 8 * h + q];
            }
        }
        __syncthreads();
        #pragma unroll
        for (int q = 0; q < 8; ++q) {
            float4 v = buf[t * 9 + q];
            Fm[32 * h + 4 * q + 0] = v.x;
            Fm[32 * h + 4 * q + 1] = v.y;
            Fm[32 * h + 4 * q + 2] = v.z;
            Fm[32 * h + 4 * q + 3] = v.w;
        }
        __syncthreads();
    }

    // ============ predict ============
    float ns[8];
    #pragma unroll
    for (int i = 0; i < 8; ++i) {
        float acc = 0.f;
        #pragma unroll
        for (int j = 0; j < 8; ++j) acc += Fm[i * 8 + j] * s[j];
        ns[i] = acc;
    }
    // newP = F P F^T + Q, column block at a time (gcol keeps peak low; this
    // exact structure measured 136 VGPR in R3)
    #pragma unroll
    for (int l = 0; l < 8; ++l) {
        float gcol[8];  // gcol[j] = (P F^T)[j][l]
        #pragma unroll
        for (int j = 0; j < 8; ++j) {
            float acc = 0.f;
            #pragma unroll
            for (int k = 0; k < 8; ++k) acc += SYM(Ps, j, k) * Fm[l * 8 + k];
            gcol[j] = acc;
        }
        #pragma unroll
        for (int i = l; i < 8; ++i) {
            float acc = Pn[TIX(i, l)];
            #pragma unroll
            for (int j = 0; j < 8; ++j) acc += Fm[i * 8 + j] * gcol[j];
            Pn[TIX(i, l)] = acc;
        }
    }
    // Fm, Ps, s dead

    // ============ stage H (8 f4/batch, pad-9 dest) -> Hm ============
    float Hm[32];
    {
        const float4* g = reinterpret_cast<const float4*>(Hin) + (size_t)bb * 8;
        #pragma unroll
        for (int i = 0; i < 8; ++i) {
            int fl = i * 64 + t;
            buf[(fl >> 3) * 9 + (fl & 7)] = g[fl];
        }
    }
    __syncthreads();
    #pragma unroll
    for (int q = 0; q < 8; ++q) {
        float4 v = buf[t * 9 + q];
        Hm[4 * q + 0] = v.x; Hm[4 * q + 1] = v.y;
        Hm[4 * q + 2] = v.z; Hm[4 * q + 3] = v.w;
    }

    // ============ residual + prediction out (direct, 16B/lane coalesced) ============
    float res[4];
    {
        float4 z = *(reinterpret_cast<const float4*>(meas) + b);
        float pr[4];
        #pragma unroll
        for (int i = 0; i < 4; ++i) {
            float acc = 0.f;
            #pragma unroll
            for (int j = 0; j < 8; ++j) acc += Hm[i * 8 + j] * ns[j];
            pr[i] = acc;
        }
        res[0] = z.x - pr[0]; res[1] = z.y - pr[1];
        res[2] = z.z - pr[2]; res[3] = z.w - pr[3];
        *(reinterpret_cast<float4*>(out_pred) + b) =
            make_float4(pr[0], pr[1], pr[2], pr[3]);
    }

    // ============ HP = H newP (4x8) ============
    float HP[32];
    #pragma unroll
    for (int i = 0; i < 4; ++i)
        #pragma unroll
        for (int k = 0; k < 8; ++k) {
            float acc = 0.f;
            #pragma unroll
            for (int j = 0; j < 8; ++j) acc += Hm[i * 8 + j] * SYM(Pn, j, k);
            HP[i * 8 + k] = acc;
        }

    // ============ Sf = HP H^T (Hm dies HERE, before R is staged) ============
    float Sf[16];
    #pragma unroll
    for (int i = 0; i < 4; ++i)
        #pragma unroll
        for (int l = 0; l <= i; ++l) {
            float acc = 0.f;
            #pragma unroll
            for (int k = 0; k < 8; ++k) acc += HP[i * 8 + k] * Hm[l * 8 + k];
            Sf[i * 4 + l] = acc;
            Sf[l * 4 + i] = acc;
        }

    // ============ stage mn (5 f2/batch) -> Sf += R; invert ============
    {
        const float2* g = reinterpret_cast<const float2*>(mnin) + (size_t)bb * 5;
        float2* buf2 = reinterpret_cast<float2*>(buf);
        #pragma unroll
        for (int i = 0; i < 5; ++i) buf2[i * 64 + t] = g[i * 64 + t];
    }
    __syncthreads();
    float Si[16];
    {
        const float2* buf2 = reinterpret_cast<const float2*>(buf);
        float Lr[10];
        #pragma unroll
        for (int p = 0; p < 5; ++p) {
            float2 v = buf2[t * 5 + p];
            Lr[2 * p] = v.x; Lr[2 * p + 1] = v.y;
        }
        #pragma unroll
        for (int i = 0; i < 4; ++i)
            #pragma unroll
            for (int j = 0; j <= i; ++j) {
                float acc = 0.f;
                #pragma unroll
                for (int k = 0; k <= j; ++k)
                    acc += Lr[TIX(i, k)] * Lr[TIX(j, k)];
                Sf[i * 4 + j] += acc;
                if (i != j) Sf[j * 4 + i] += acc;
            }
        inv4(Sf, Si);
    }

    // ============ upd_state = ns + HP^T (Si res) ============
    float us[8];
    {
        float w[4];
        #pragma unroll
        for (int a = 0; a < 4; ++a) {
            float acc = 0.f;
            #pragma unroll
            for (int c = 0; c < 4; ++c) acc += Si[a * 4 + c] * res[c];
            w[a] = acc;
        }
        #pragma unroll
        for (int i = 0; i < 8; ++i) {
            float acc = ns[i];
            #pragma unroll
            for (int a = 0; a < 4; ++a) acc += HP[a * 8 + i] * w[a];
            us[i] = acc;
        }
    }

    // ============ stage upd_state out (pad-3 layout) ============
    buf[t * 3 + 0] = make_float4(us[0], us[1], us[2], us[3]);
    buf[t * 3 + 1] = make_float4(us[4], us[5], us[6], us[7]);
    __syncthreads();
    {
        float4* g = reinterpret_cast<float4*>(out_state) + (size_t)bb * 2;
        #pragma unroll
        for (int i = 0; i < 2; ++i) {
            int f = i * 64 + t;
            g[f] = buf[(f >> 1) * 3 + (f & 1)];
        }
    }

    // ============ upd_cov = Pn - HP^T (Si HP), in place (symmetric) ============
    {
        float M[32];  // M = Si HP (4x8)
        #pragma unroll
        for (int a = 0; a < 4; ++a)
            #pragma unroll
            for (int j = 0; j < 8; ++j) {
                float acc = 0.f;
                #pragma unroll
                for (int c = 0; c < 4; ++c) acc += Si[a * 4 + c] * HP[c * 8 + j];
                M[a * 8 + j] = acc;
            }
        #pragma unroll
        for (int i = 0; i < 8; ++i)
            #pragma unroll
            for (int l = 0; l <= i; ++l) {
                float acc = Pn[TIX(i, l)];
                #pragma unroll
                for (int a = 0; a < 4; ++a) acc -= HP[a * 8 + i] * M[a * 8 + l];
                Pn[TIX(i, l)] = acc;
            }
    }

    // ============ cov out: two row-halves through LDS, mirrored ============
    #pragma unroll
    for (int h = 0; h < 2; ++h) {
        #pragma unroll
        for (int r = 0; r < 4; ++r) {
            const int i = 4 * h + r;
            buf[t * 9 + 2 * r + 0] = make_float4(SYM(Pn, i, 0), SYM(Pn, i, 1),
                                                 SYM(Pn, i, 2), SYM(Pn, i, 3));
            buf[t * 9 + 2 * r + 1] = make_float4(SYM(Pn, i, 4), SYM(Pn, i, 5),
                                                 SYM(Pn, i, 6), SYM(Pn, i, 7));
        }
        __syncthreads();
        {
            float4* g = reinterpret_cast<float4*>(out_cov) + (size_t)bb * 16;
            #pragma unroll
            for (int i = 0; i < 8; ++i) {
                int fl = i * 64 + t;
                int bq = fl >> 3, q = fl & 7;
                g[bq * 16 + 8 * h + q] = buf[bq * 9 + q];
            }
        }
        __syncthreads();
    }
}

extern "C" void kernel_launch(void* const* d_in, const int* in_sizes, int n_in,
                              void* d_out, int out_size, void* d_ws, size_t ws_size,
                              hipStream_t stream) {
    const float* meas  = (const float*)d_in[0];
    const float* state = (const float*)d_in[1];
    const float* Pin   = (const float*)d_in[2];
    const float* Fin   = (const float*)d_in[3];
    const float* Hin   = (const float*)d_in[4];
    const float* pn    = (const float*)d_in[5];
    const float* mn    = (const float*)d_in[6];

    const int B = in_sizes[1] / 8;  // state is (B, 8); B = 262144 (divisible by 64)

    float* out = (float*)d_out;
    float* out_pred  = out;                       // B*4
    float* out_state = out + (size_t)B * 4;       // B*8
    float* out_cov   = out + (size_t)B * 12;      // B*64

    dim3 block(64);
    dim3 grid(B / 64);
    ekf_kernel<<<grid, block, 0, stream>>>(meas, state, Pin, Fin, Hin, pn, mn,
                                           out_pred, out_state, out_cov);
}